// Round 6
// baseline (111.112 us; speedup 1.0000x reference)
//
#include <hip/hip_runtime.h>
#include <hip/hip_bf16.h>

// Problem constants
#define NN 64
#define BB 256
#define DD 1792
#define KK 35
#define PP 10
#define DQ 448          // D / 4 (float4s per row)
#define WR 16           // rows per weights-block
#define AR 8            // rows per apply-block
#define NGRP 28         // 16-lane groups per 448-thread block

typedef float fx4 __attribute__((ext_vector_type(4)));

// Single-instruction DPP add; 4-step sequence leaves the 16-lane-group sum
// in lane 15 of each group.
__device__ __forceinline__ float group16_sum_dpp(float x) {
    asm("v_add_f32_dpp %0, %0, %0 row_shr:1 row_mask:0xf bank_mask:0xf bound_ctrl:0" : "+v"(x));
    asm("v_add_f32_dpp %0, %0, %0 row_shr:2 row_mask:0xf bank_mask:0xf bound_ctrl:0" : "+v"(x));
    asm("v_add_f32_dpp %0, %0, %0 row_shr:4 row_mask:0xf bank_mask:0xf bound_ctrl:0" : "+v"(x));
    asm("v_add_f32_dpp %0, %0, %0 row_shr:8 row_mask:0xf bank_mask:0xf bound_ctrl:0" : "+v"(x));
    return x;
}

// ---------------------------------------------------------------------------
// K1: Gf = gamma * W_net; sG[p] = sum(Gf[p]); zc[p] = dot(beta,Wnet[p]) + b_net[p]
// ---------------------------------------------------------------------------
__global__ void prep_gf(const float* __restrict__ gamma, const float* __restrict__ beta,
                        const float* __restrict__ Wnet, const float* __restrict__ bnet,
                        float* __restrict__ GF, float* __restrict__ SG, float* __restrict__ ZC) {
    const int p = blockIdx.x;
    const int tid = threadIdx.x;
    float sg = 0.f, sb = 0.f;
#pragma unroll
    for (int j = 0; j < 7; ++j) {
        int d = j * 256 + tid;
        float wv = Wnet[p * DD + d];
        float g = gamma[d] * wv;
        GF[p * DD + d] = g;
        sg += g;
        sb += beta[d] * wv;
    }
#pragma unroll
    for (int off = 32; off > 0; off >>= 1) {
        sg += __shfl_xor(sg, off);
        sb += __shfl_xor(sb, off);
    }
    __shared__ float rs[4][2];
    if ((tid & 63) == 0) { rs[tid >> 6][0] = sg; rs[tid >> 6][1] = sb; }
    __syncthreads();
    if (tid == 0) {
        float a = 0.f, c = 0.f;
#pragma unroll
        for (int w = 0; w < 4; ++w) { a += rs[w][0]; c += rs[w][1]; }
        SG[p] = a;
        ZC[p] = c + bnet[p];
    }
}

// ---------------------------------------------------------------------------
// K2: bank[b][r] = dot(task[b], Wtok[r]) + btok[r]; ptok[b][d] likewise.
// ---------------------------------------------------------------------------
__global__ void prep_bank(const float* __restrict__ task,
                          const float* __restrict__ Wtok, const float* __restrict__ btok,
                          const float* __restrict__ Wptok, const float* __restrict__ bptok,
                          float* __restrict__ bank, float* __restrict__ ptok) {
    __shared__ float ti[32 * KK];
    const int tid = threadIdx.x;
    const int b0 = blockIdx.y * 32;
    for (int i = tid; i < 32 * KK; i += 256) ti[i] = task[b0 * KK + i];

    const int r = blockIdx.x * 256 + tid;
    const bool isbank = (r < PP * DD);
    const int rr = isbank ? r : (r - PP * DD);
    const float* __restrict__ W = isbank ? Wtok : Wptok;
    const float bias = isbank ? btok[r] : bptok[rr];

    float w[KK];
#pragma unroll
    for (int k = 0; k < KK; ++k) w[k] = W[rr * KK + k];

    __syncthreads();
#pragma unroll 1
    for (int bb = 0; bb < 32; ++bb) {
        float acc = bias;
#pragma unroll
        for (int k = 0; k < KK; ++k) acc = fmaf(ti[bb * KK + k], w[k], acc);
        const int b = b0 + bb;
        if (isbank) bank[b * (PP * DD) + r] = acc;
        else        ptok[b * DD + rr]       = acc;
    }
}

// ---------------------------------------------------------------------------
// K3 (weights): per block (b, 16 rows), 448 threads. Streaming read of X with
// a 4-deep named-register prefetch ring; per-row {s1,s2,10 dots} partials via
// DPP group-16 reduce; lane-15 writes to LDS; ONE barrier at the end; 256
// threads finalize 16 rows' sigmoids and write w[n][b][p] to global.
// No barrier in the row loop -> vmcnt never drains, loads stream at BW.
// ---------------------------------------------------------------------------
__global__ __launch_bounds__(448) void weights_kernel(
    const float* __restrict__ X, const float* __restrict__ PTOK,
    const float* __restrict__ GF, const float* __restrict__ SG,
    const float* __restrict__ ZC, float* __restrict__ Wout) {
    const int tid = threadIdx.x;
    const int b = blockIdx.y;
    const int n0 = blockIdx.x * WR;

    const float4* __restrict__ X4 = (const float4*)X;
    const float4* __restrict__ G4 = (const float4*)GF;
    const float4* __restrict__ P4 = (const float4*)PTOK;

    __shared__ float red[WR][NGRP][12];

    float4 gf[PP];
#pragma unroll
    for (int p = 0; p < PP; ++p) gf[p] = G4[p * DQ + tid];
    const float4 ptk = P4[b * DQ + tid];
    const bool writer = ((tid & 15) == 15);
    const int g = tid >> 4;

    const size_t rstride = (size_t)BB * DQ;
    const size_t idx0 = ((size_t)n0 * BB + b) * DQ + tid;

    float4 x0 = X4[idx0];
    float4 x1 = X4[idx0 + rstride];
    float4 x2 = X4[idx0 + 2 * rstride];
    float4 x3 = X4[idx0 + 3 * rstride];

#define WSTEP(r, xv, LOADSTMT)                                                        \
    {                                                                                 \
        float4 t;                                                                     \
        t.x = xv.x + ptk.x; t.y = xv.y + ptk.y;                                       \
        t.z = xv.z + ptk.z; t.w = xv.w + ptk.w;                                       \
        LOADSTMT;                                                                     \
        float s1 = t.x + t.y + t.z + t.w;                                             \
        float s2 = t.x * t.x;                                                         \
        s2 = fmaf(t.y, t.y, s2); s2 = fmaf(t.z, t.z, s2); s2 = fmaf(t.w, t.w, s2);    \
        float a[PP];                                                                  \
        _Pragma("unroll")                                                             \
        for (int p = 0; p < PP; ++p) {                                                \
            float v = t.x * gf[p].x;                                                  \
            v = fmaf(t.y, gf[p].y, v);                                                \
            v = fmaf(t.z, gf[p].z, v);                                                \
            v = fmaf(t.w, gf[p].w, v);                                                \
            a[p] = v;                                                                 \
        }                                                                             \
        s1 = group16_sum_dpp(s1);                                                     \
        s2 = group16_sum_dpp(s2);                                                     \
        _Pragma("unroll")                                                             \
        for (int p = 0; p < PP; ++p) a[p] = group16_sum_dpp(a[p]);                    \
        if (writer) {                                                                 \
            float4* dst = (float4*)&red[r][g][0];                                     \
            dst[0] = make_float4(s1, s2, a[0], a[1]);                                 \
            dst[1] = make_float4(a[2], a[3], a[4], a[5]);                             \
            dst[2] = make_float4(a[6], a[7], a[8], a[9]);                             \
        }                                                                             \
    }

    WSTEP(0,  x0, x0 = X4[idx0 + 4 * rstride])
    WSTEP(1,  x1, x1 = X4[idx0 + 5 * rstride])
    WSTEP(2,  x2, x2 = X4[idx0 + 6 * rstride])
    WSTEP(3,  x3, x3 = X4[idx0 + 7 * rstride])
    WSTEP(4,  x0, x0 = X4[idx0 + 8 * rstride])
    WSTEP(5,  x1, x1 = X4[idx0 + 9 * rstride])
    WSTEP(6,  x2, x2 = X4[idx0 + 10 * rstride])
    WSTEP(7,  x3, x3 = X4[idx0 + 11 * rstride])
    WSTEP(8,  x0, x0 = X4[idx0 + 12 * rstride])
    WSTEP(9,  x1, x1 = X4[idx0 + 13 * rstride])
    WSTEP(10, x2, x2 = X4[idx0 + 14 * rstride])
    WSTEP(11, x3, x3 = X4[idx0 + 15 * rstride])
    WSTEP(12, x0, )
    WSTEP(13, x1, )
    WSTEP(14, x2, )
    WSTEP(15, x3, )
#undef WSTEP

    __syncthreads();

    if (tid < 256) {
        const int row = tid >> 4;
        const int v = tid & 15;
        float f = 0.f;
        if (v < 12) {
#pragma unroll
            for (int q = 0; q < NGRP; ++q) f += red[row][q][v];
        }
        const int base = (tid & 63) & ~15;
        const float mu = __shfl(f, base)     * (1.0f / (float)DD);
        const float ms = __shfl(f, base + 1) * (1.0f / (float)DD);
        const float istd = rsqrtf(ms - mu * mu + 1e-5f);
        if (v >= 2 && v < 12) {
            const int p = v - 2;
            const float z = istd * (f - mu * SG[p]) + ZC[p];
            Wout[((size_t)(n0 + row) * BB + b) * PP + p] = 1.0f / (1.0f + __expf(-z));
        }
    }
}

// ---------------------------------------------------------------------------
// K4 (apply): per block (b, 8 rows), 448 threads. out = X + w @ bank.
// bank in 10 regs (L2-resident), w via tiny LDS stage, X read (L3-resident
// after weights_kernel), nontemporal stores keep out from evicting X in L3.
// ---------------------------------------------------------------------------
__global__ __launch_bounds__(448) void apply_kernel(
    const float* __restrict__ X, const float* __restrict__ BANK,
    const float* __restrict__ W, float* __restrict__ OUT) {
    const int tid = threadIdx.x;
    const int b = blockIdx.y;
    const int n0 = blockIdx.x * AR;

    const float4* __restrict__ X4 = (const float4*)X;
    const float4* __restrict__ B4 = (const float4*)BANK;
    fx4* __restrict__ O4 = (fx4*)OUT;

    __shared__ float wl[AR][PP];

    // w -> LDS first (its ds_write drains only its own load)
    if (tid < AR * PP) {
        const int r = tid / PP, p = tid % PP;
        wl[r][p] = W[((size_t)(n0 + r) * BB + b) * PP + p];
    }

    const size_t rstride = (size_t)BB * DQ;
    const size_t idx0 = ((size_t)n0 * BB + b) * DQ + tid;

    float4 x[AR];
#pragma unroll
    for (int r = 0; r < AR; ++r) x[r] = X4[idx0 + (size_t)r * rstride];

    float4 bk[PP];
#pragma unroll
    for (int p = 0; p < PP; ++p) bk[p] = B4[((size_t)b * PP + p) * DQ + tid];

    __syncthreads();

#pragma unroll
    for (int r = 0; r < AR; ++r) {
        float4 acc = x[r];
#pragma unroll
        for (int p = 0; p < PP; ++p) {
            const float wv = wl[r][p];
            acc.x = fmaf(wv, bk[p].x, acc.x);
            acc.y = fmaf(wv, bk[p].y, acc.y);
            acc.z = fmaf(wv, bk[p].z, acc.z);
            acc.w = fmaf(wv, bk[p].w, acc.w);
        }
        fx4 av;
        av.x = acc.x; av.y = acc.y; av.z = acc.z; av.w = acc.w;
        __builtin_nontemporal_store(av, &O4[idx0 + (size_t)r * rstride]);
    }
}

// ---------------------------------------------------------------------------
extern "C" void kernel_launch(void* const* d_in, const int* in_sizes, int n_in,
                              void* d_out, int out_size, void* d_ws, size_t ws_size,
                              hipStream_t stream) {
    const float* X     = (const float*)d_in[0];
    const float* task  = (const float*)d_in[1];
    const float* Wtok  = (const float*)d_in[2];
    const float* btok  = (const float*)d_in[3];
    const float* Wptok = (const float*)d_in[4];
    const float* bptok = (const float*)d_in[5];
    const float* gamma = (const float*)d_in[6];
    const float* beta  = (const float*)d_in[7];
    const float* Wnet  = (const float*)d_in[8];
    const float* bnet  = (const float*)d_in[9];
    float* out = (float*)d_out;

    float* ws = (float*)d_ws;
    float* bank = ws;                                  // B*P*D = 4,587,520
    float* ptok = bank + (size_t)BB * PP * DD;         // B*D   =   458,752
    float* GF   = ptok + (size_t)BB * DD;              // P*D   =    17,920
    float* SG   = GF + PP * DD;                        // P
    float* ZC   = SG + PP;                             // P
    float* Wout = ZC + PP;                             // N*B*P =   163,840

    prep_gf<<<PP, 256, 0, stream>>>(gamma, beta, Wnet, bnet, GF, SG, ZC);
    prep_bank<<<dim3(77, 8), 256, 0, stream>>>(task, Wtok, btok, Wptok, bptok, bank, ptok);
    weights_kernel<<<dim3(NN / WR, BB), 448, 0, stream>>>(X, ptok, GF, SG, ZC, Wout);
    apply_kernel<<<dim3(NN / AR, BB), 448, 0, stream>>>(X, bank, Wout, out);
}

// Round 7
// 102.188 us; speedup vs baseline: 1.0873x; 1.0873x over previous
//
#include <hip/hip_runtime.h>
#include <hip/hip_bf16.h>

// Problem constants
#define NN 64
#define BB 256
#define DD 1792
#define KK 35
#define PP 10
#define DQ 448          // D / 4 (float4s per row)
#define WR 16           // rows per weights-block
#define AR 16           // rows per apply-block
#define NGRP 28         // 16-lane groups per 448-thread block

// Single-instruction DPP add; 4-step sequence leaves the 16-lane-group sum
// in lane 15 of each group.
__device__ __forceinline__ float group16_sum_dpp(float x) {
    asm("v_add_f32_dpp %0, %0, %0 row_shr:1 row_mask:0xf bank_mask:0xf bound_ctrl:0" : "+v"(x));
    asm("v_add_f32_dpp %0, %0, %0 row_shr:2 row_mask:0xf bank_mask:0xf bound_ctrl:0" : "+v"(x));
    asm("v_add_f32_dpp %0, %0, %0 row_shr:4 row_mask:0xf bank_mask:0xf bound_ctrl:0" : "+v"(x));
    asm("v_add_f32_dpp %0, %0, %0 row_shr:8 row_mask:0xf bank_mask:0xf bound_ctrl:0" : "+v"(x));
    return x;
}

// ---------------------------------------------------------------------------
// K1: Gf = gamma * W_net; sG[p] = sum(Gf[p]); zc[p] = dot(beta,Wnet[p]) + b_net[p]
// ---------------------------------------------------------------------------
__global__ void prep_gf(const float* __restrict__ gamma, const float* __restrict__ beta,
                        const float* __restrict__ Wnet, const float* __restrict__ bnet,
                        float* __restrict__ GF, float* __restrict__ SG, float* __restrict__ ZC) {
    const int p = blockIdx.x;
    const int tid = threadIdx.x;
    float sg = 0.f, sb = 0.f;
#pragma unroll
    for (int j = 0; j < 7; ++j) {
        int d = j * 256 + tid;
        float wv = Wnet[p * DD + d];
        float g = gamma[d] * wv;
        GF[p * DD + d] = g;
        sg += g;
        sb += beta[d] * wv;
    }
#pragma unroll
    for (int off = 32; off > 0; off >>= 1) {
        sg += __shfl_xor(sg, off);
        sb += __shfl_xor(sb, off);
    }
    __shared__ float rs[4][2];
    if ((tid & 63) == 0) { rs[tid >> 6][0] = sg; rs[tid >> 6][1] = sb; }
    __syncthreads();
    if (tid == 0) {
        float a = 0.f, c = 0.f;
#pragma unroll
        for (int w = 0; w < 4; ++w) { a += rs[w][0]; c += rs[w][1]; }
        SG[p] = a;
        ZC[p] = c + bnet[p];
    }
}

// ---------------------------------------------------------------------------
// K2: bank[b][r] = dot(task[b], Wtok[r]) + btok[r]; ptok[b][d] likewise.
// ---------------------------------------------------------------------------
__global__ void prep_bank(const float* __restrict__ task,
                          const float* __restrict__ Wtok, const float* __restrict__ btok,
                          const float* __restrict__ Wptok, const float* __restrict__ bptok,
                          float* __restrict__ bank, float* __restrict__ ptok) {
    __shared__ float ti[32 * KK];
    const int tid = threadIdx.x;
    const int b0 = blockIdx.y * 32;
    for (int i = tid; i < 32 * KK; i += 256) ti[i] = task[b0 * KK + i];

    const int r = blockIdx.x * 256 + tid;
    const bool isbank = (r < PP * DD);
    const int rr = isbank ? r : (r - PP * DD);
    const float* __restrict__ W = isbank ? Wtok : Wptok;
    const float bias = isbank ? btok[r] : bptok[rr];

    float w[KK];
#pragma unroll
    for (int k = 0; k < KK; ++k) w[k] = W[rr * KK + k];

    __syncthreads();
#pragma unroll 1
    for (int bb = 0; bb < 32; ++bb) {
        float acc = bias;
#pragma unroll
        for (int k = 0; k < KK; ++k) acc = fmaf(ti[bb * KK + k], w[k], acc);
        const int b = b0 + bb;
        if (isbank) bank[b * (PP * DD) + r] = acc;
        else        ptok[b * DD + rr]       = acc;
    }
}

// ---------------------------------------------------------------------------
// K3 (weights): per block (b, 16 rows), 448 threads. Streaming read of X with
// an 8-deep register prefetch ring (8 KB/wave in flight -> covers HBM
// latency); per-row {s1,s2,10 dots} partials via DPP group-16 reduce; lane-15
// writes partials to LDS; ONE barrier; 256 threads finalize 16 sigmoid rows.
// ---------------------------------------------------------------------------
__global__ __launch_bounds__(448) void weights_kernel(
    const float* __restrict__ X, const float* __restrict__ PTOK,
    const float* __restrict__ GF, const float* __restrict__ SG,
    const float* __restrict__ ZC, float* __restrict__ Wout) {
    const int tid = threadIdx.x;
    const int b = blockIdx.y;
    const int n0 = blockIdx.x * WR;

    const float4* __restrict__ X4 = (const float4*)X;
    const float4* __restrict__ G4 = (const float4*)GF;
    const float4* __restrict__ P4 = (const float4*)PTOK;

    __shared__ float red[WR][NGRP][12];

    float4 gf[PP];
#pragma unroll
    for (int p = 0; p < PP; ++p) gf[p] = G4[p * DQ + tid];
    const float4 ptk = P4[b * DQ + tid];
    const bool writer = ((tid & 15) == 15);
    const int g = tid >> 4;

    const size_t rstride = (size_t)BB * DQ;
    const size_t idx0 = ((size_t)n0 * BB + b) * DQ + tid;

    float4 xr[8];
#pragma unroll
    for (int j = 0; j < 8; ++j) xr[j] = X4[idx0 + (size_t)j * rstride];

#pragma unroll
    for (int r = 0; r < WR; ++r) {
        float4 x = xr[r & 7];
        if (r < 8) xr[r & 7] = X4[idx0 + (size_t)(r + 8) * rstride];

        float4 t;
        t.x = x.x + ptk.x; t.y = x.y + ptk.y;
        t.z = x.z + ptk.z; t.w = x.w + ptk.w;

        float s1 = t.x + t.y + t.z + t.w;
        float s2 = t.x * t.x;
        s2 = fmaf(t.y, t.y, s2); s2 = fmaf(t.z, t.z, s2); s2 = fmaf(t.w, t.w, s2);
        float a[PP];
#pragma unroll
        for (int p = 0; p < PP; ++p) {
            float v = t.x * gf[p].x;
            v = fmaf(t.y, gf[p].y, v);
            v = fmaf(t.z, gf[p].z, v);
            v = fmaf(t.w, gf[p].w, v);
            a[p] = v;
        }
        s1 = group16_sum_dpp(s1);
        s2 = group16_sum_dpp(s2);
#pragma unroll
        for (int p = 0; p < PP; ++p) a[p] = group16_sum_dpp(a[p]);

        if (writer) {
            float4* dst = (float4*)&red[r][g][0];
            dst[0] = make_float4(s1, s2, a[0], a[1]);
            dst[1] = make_float4(a[2], a[3], a[4], a[5]);
            dst[2] = make_float4(a[6], a[7], a[8], a[9]);
        }
    }

    __syncthreads();

    if (tid < 256) {
        const int row = tid >> 4;
        const int v = tid & 15;
        float f = 0.f;
        if (v < 12) {
#pragma unroll
            for (int q = 0; q < NGRP; ++q) f += red[row][q][v];
        }
        const int base = (tid & 63) & ~15;
        const float mu = __shfl(f, base)     * (1.0f / (float)DD);
        const float ms = __shfl(f, base + 1) * (1.0f / (float)DD);
        const float istd = rsqrtf(ms - mu * mu + 1e-5f);
        if (v >= 2 && v < 12) {
            const int p = v - 2;
            const float z = istd * (f - mu * SG[p]) + ZC[p];
            Wout[((size_t)(n0 + row) * BB + b) * PP + p] = 1.0f / (1.0f + __expf(-z));
        }
    }
}

// ---------------------------------------------------------------------------
// K4 (apply): per block (b, 16 rows), 448 threads. out = X + w @ bank.
// ZERO LDS, ZERO barriers. bank in 10 regs amortized over 16 rows; w read as
// uniform (scalar) loads per row; 8-deep X prefetch ring; plain stores.
// Structurally a pure stream: load -> 40 fma -> store.
// ---------------------------------------------------------------------------
__global__ __launch_bounds__(448) void apply_kernel(
    const float* __restrict__ X, const float* __restrict__ BANK,
    const float* __restrict__ W, float* __restrict__ OUT) {
    const int tid = threadIdx.x;
    const int b = blockIdx.y;
    const int n0 = blockIdx.x * AR;

    const float4* __restrict__ X4 = (const float4*)X;
    const float4* __restrict__ B4 = (const float4*)BANK;
    float4* __restrict__ O4 = (float4*)OUT;

    float4 bk[PP];
#pragma unroll
    for (int p = 0; p < PP; ++p) bk[p] = B4[((size_t)b * PP + p) * DQ + tid];

    const size_t rstride = (size_t)BB * DQ;
    const size_t idx0 = ((size_t)n0 * BB + b) * DQ + tid;

    float4 xr[8];
#pragma unroll
    for (int j = 0; j < 8; ++j) xr[j] = X4[idx0 + (size_t)j * rstride];

#pragma unroll
    for (int r = 0; r < AR; ++r) {
        float4 acc = xr[r & 7];
        if (r < 8) xr[r & 7] = X4[idx0 + (size_t)(r + 8) * rstride];

        const float* __restrict__ wn = W + ((size_t)(n0 + r) * BB + b) * PP;
        float wv[PP];
#pragma unroll
        for (int p = 0; p < PP; ++p) wv[p] = wn[p];   // uniform -> scalar loads

#pragma unroll
        for (int p = 0; p < PP; ++p) {
            acc.x = fmaf(wv[p], bk[p].x, acc.x);
            acc.y = fmaf(wv[p], bk[p].y, acc.y);
            acc.z = fmaf(wv[p], bk[p].z, acc.z);
            acc.w = fmaf(wv[p], bk[p].w, acc.w);
        }
        O4[idx0 + (size_t)r * rstride] = acc;
    }
}

// ---------------------------------------------------------------------------
extern "C" void kernel_launch(void* const* d_in, const int* in_sizes, int n_in,
                              void* d_out, int out_size, void* d_ws, size_t ws_size,
                              hipStream_t stream) {
    const float* X     = (const float*)d_in[0];
    const float* task  = (const float*)d_in[1];
    const float* Wtok  = (const float*)d_in[2];
    const float* btok  = (const float*)d_in[3];
    const float* Wptok = (const float*)d_in[4];
    const float* bptok = (const float*)d_in[5];
    const float* gamma = (const float*)d_in[6];
    const float* beta  = (const float*)d_in[7];
    const float* Wnet  = (const float*)d_in[8];
    const float* bnet  = (const float*)d_in[9];
    float* out = (float*)d_out;

    float* ws = (float*)d_ws;
    float* bank = ws;                                  // B*P*D = 4,587,520
    float* ptok = bank + (size_t)BB * PP * DD;         // B*D   =   458,752
    float* GF   = ptok + (size_t)BB * DD;              // P*D   =    17,920
    float* SG   = GF + PP * DD;                        // P
    float* ZC   = SG + PP;                             // P
    float* Wout = ZC + PP;                             // N*B*P =   163,840

    prep_gf<<<PP, 256, 0, stream>>>(gamma, beta, Wnet, bnet, GF, SG, ZC);
    prep_bank<<<dim3(77, 8), 256, 0, stream>>>(task, Wtok, btok, Wptok, bptok, bank, ptok);
    weights_kernel<<<dim3(NN / WR, BB), 448, 0, stream>>>(X, ptok, GF, SG, ZC, Wout);
    apply_kernel<<<dim3(NN / AR, BB), 448, 0, stream>>>(X, bank, Wout, out);
}

// Round 8
// 90.124 us; speedup vs baseline: 1.2329x; 1.1339x over previous
//
#include <hip/hip_runtime.h>
#include <hip/hip_bf16.h>

// Problem constants
#define NN 64
#define BB 256
#define DD 1792
#define KK 35
#define PP 10
#define DQ 448          // D / 4 (float4s per row)
#define FR 8            // rows per fused-block
#define NGRP 28         // 16-lane groups per 448-thread block

// Single-instruction DPP add; 4-step sequence leaves the 16-lane-group sum
// in lane 15 of each group.
__device__ __forceinline__ float group16_sum_dpp(float x) {
    asm("v_add_f32_dpp %0, %0, %0 row_shr:1 row_mask:0xf bank_mask:0xf bound_ctrl:0" : "+v"(x));
    asm("v_add_f32_dpp %0, %0, %0 row_shr:2 row_mask:0xf bank_mask:0xf bound_ctrl:0" : "+v"(x));
    asm("v_add_f32_dpp %0, %0, %0 row_shr:4 row_mask:0xf bank_mask:0xf bound_ctrl:0" : "+v"(x));
    asm("v_add_f32_dpp %0, %0, %0 row_shr:8 row_mask:0xf bank_mask:0xf bound_ctrl:0" : "+v"(x));
    return x;
}

// ---------------------------------------------------------------------------
// K1: Gf = gamma * W_net; sG[p] = sum(Gf[p]); zc[p] = dot(beta,Wnet[p]) + b_net[p]
// ---------------------------------------------------------------------------
__global__ void prep_gf(const float* __restrict__ gamma, const float* __restrict__ beta,
                        const float* __restrict__ Wnet, const float* __restrict__ bnet,
                        float* __restrict__ GF, float* __restrict__ SG, float* __restrict__ ZC) {
    const int p = blockIdx.x;
    const int tid = threadIdx.x;
    float sg = 0.f, sb = 0.f;
#pragma unroll
    for (int j = 0; j < 7; ++j) {
        int d = j * 256 + tid;
        float wv = Wnet[p * DD + d];
        float g = gamma[d] * wv;
        GF[p * DD + d] = g;
        sg += g;
        sb += beta[d] * wv;
    }
#pragma unroll
    for (int off = 32; off > 0; off >>= 1) {
        sg += __shfl_xor(sg, off);
        sb += __shfl_xor(sb, off);
    }
    __shared__ float rs[4][2];
    if ((tid & 63) == 0) { rs[tid >> 6][0] = sg; rs[tid >> 6][1] = sb; }
    __syncthreads();
    if (tid == 0) {
        float a = 0.f, c = 0.f;
#pragma unroll
        for (int w = 0; w < 4; ++w) { a += rs[w][0]; c += rs[w][1]; }
        SG[p] = a;
        ZC[p] = c + bnet[p];
    }
}

// ---------------------------------------------------------------------------
// K2: bank[b][r] = dot(task[b], Wtok[r]) + btok[r]; ptok[b][d] likewise.
// ---------------------------------------------------------------------------
__global__ void prep_bank(const float* __restrict__ task,
                          const float* __restrict__ Wtok, const float* __restrict__ btok,
                          const float* __restrict__ Wptok, const float* __restrict__ bptok,
                          float* __restrict__ bank, float* __restrict__ ptok) {
    __shared__ float ti[32 * KK];
    const int tid = threadIdx.x;
    const int b0 = blockIdx.y * 32;
    for (int i = tid; i < 32 * KK; i += 256) ti[i] = task[b0 * KK + i];

    const int r = blockIdx.x * 256 + tid;
    const bool isbank = (r < PP * DD);
    const int rr = isbank ? r : (r - PP * DD);
    const float* __restrict__ W = isbank ? Wtok : Wptok;
    const float bias = isbank ? btok[r] : bptok[rr];

    float w[KK];
#pragma unroll
    for (int k = 0; k < KK; ++k) w[k] = W[rr * KK + k];

    __syncthreads();
#pragma unroll 1
    for (int bb = 0; bb < 32; ++bb) {
        float acc = bias;
#pragma unroll
        for (int k = 0; k < KK; ++k) acc = fmaf(ti[bb * KK + k], w[k], acc);
        const int b = b0 + bb;
        if (isbank) bank[b * (PP * DD) + r] = acc;
        else        ptok[b * DD + rr]       = acc;
    }
}

// ---------------------------------------------------------------------------
// K3 (fused): per block (b, 8 rows), 448 threads, ONE phase boundary.
//   1. Issue gf + ptk + ALL 8 X row loads (X stays in registers).
//   2. Phase 1: per-row {s1,s2,10 dots} partials via DPP group-16 reduce;
//      lane-15 writes partials to LDS (no sync).
//   3. Issue bank loads (cover the finalize latency).
//   4. barrier -> finalize 8 rows' sigmoids into wlds -> barrier.
//   5. Phase 2: out = x[r] + sum_p w*bank from REGISTERS (fma+store only).
// 2048 blocks pipeline across CUs; no intra-block load serialization.
// ---------------------------------------------------------------------------
__global__ __launch_bounds__(448) void fused_kernel(
    const float* __restrict__ X, const float* __restrict__ BANK,
    const float* __restrict__ PTOK, const float* __restrict__ GF,
    const float* __restrict__ SG, const float* __restrict__ ZC,
    float* __restrict__ OUT) {
    const int tid = threadIdx.x;
    const int b = blockIdx.y;
    const int n0 = blockIdx.x * FR;

    const float4* __restrict__ X4 = (const float4*)X;
    const float4* __restrict__ B4 = (const float4*)BANK;
    const float4* __restrict__ G4 = (const float4*)GF;
    const float4* __restrict__ P4 = (const float4*)PTOK;
    float4* __restrict__ O4 = (float4*)OUT;

    __shared__ float red[FR][NGRP][12];
    __shared__ float wlds[FR][PP];

    const size_t rstride = (size_t)BB * DQ;
    const size_t idx0 = ((size_t)n0 * BB + b) * DQ + tid;

    // ---- issue everything phase 1 needs up front ----
    float4 gf[PP];
#pragma unroll
    for (int p = 0; p < PP; ++p) gf[p] = G4[p * DQ + tid];
    const float4 ptk = P4[b * DQ + tid];
    float4 x[FR];
#pragma unroll
    for (int r = 0; r < FR; ++r) x[r] = X4[idx0 + (size_t)r * rstride];

    const bool writer = ((tid & 15) == 15);
    const int g = tid >> 4;

    // ---- phase 1 ----
#pragma unroll
    for (int r = 0; r < FR; ++r) {
        float4 t;
        t.x = x[r].x + ptk.x; t.y = x[r].y + ptk.y;
        t.z = x[r].z + ptk.z; t.w = x[r].w + ptk.w;

        float s1 = t.x + t.y + t.z + t.w;
        float s2 = t.x * t.x;
        s2 = fmaf(t.y, t.y, s2); s2 = fmaf(t.z, t.z, s2); s2 = fmaf(t.w, t.w, s2);
        float a[PP];
#pragma unroll
        for (int p = 0; p < PP; ++p) {
            float v = t.x * gf[p].x;
            v = fmaf(t.y, gf[p].y, v);
            v = fmaf(t.z, gf[p].z, v);
            v = fmaf(t.w, gf[p].w, v);
            a[p] = v;
        }
        s1 = group16_sum_dpp(s1);
        s2 = group16_sum_dpp(s2);
#pragma unroll
        for (int p = 0; p < PP; ++p) a[p] = group16_sum_dpp(a[p]);

        if (writer) {
            float4* dst = (float4*)&red[r][g][0];
            dst[0] = make_float4(s1, s2, a[0], a[1]);
            dst[1] = make_float4(a[2], a[3], a[4], a[5]);
            dst[2] = make_float4(a[6], a[7], a[8], a[9]);
        }
    }

    // ---- issue bank loads before the barrier (covers finalize) ----
    float4 bk[PP];
#pragma unroll
    for (int p = 0; p < PP; ++p) bk[p] = B4[((size_t)b * PP + p) * DQ + tid];

    __syncthreads();

    // ---- finalize 8 rows' weights (128 threads) ----
    if (tid < FR * 16) {
        const int row = tid >> 4;
        const int v = tid & 15;
        float f = 0.f;
        if (v < 12) {
#pragma unroll
            for (int q = 0; q < NGRP; ++q) f += red[row][q][v];
        }
        const int base = (tid & 63) & ~15;
        const float mu = __shfl(f, base)     * (1.0f / (float)DD);
        const float ms = __shfl(f, base + 1) * (1.0f / (float)DD);
        const float istd = rsqrtf(ms - mu * mu + 1e-5f);
        if (v >= 2 && v < 12) {
            const int p = v - 2;
            const float z = istd * (f - mu * SG[p]) + ZC[p];
            wlds[row][p] = 1.0f / (1.0f + __expf(-z));
        }
    }
    __syncthreads();

    // ---- phase 2: out = x + w @ bank, straight from registers ----
#pragma unroll
    for (int r = 0; r < FR; ++r) {
        float4 acc = x[r];
#pragma unroll
        for (int p = 0; p < PP; ++p) {
            const float wv = wlds[r][p];
            acc.x = fmaf(wv, bk[p].x, acc.x);
            acc.y = fmaf(wv, bk[p].y, acc.y);
            acc.z = fmaf(wv, bk[p].z, acc.z);
            acc.w = fmaf(wv, bk[p].w, acc.w);
        }
        O4[idx0 + (size_t)r * rstride] = acc;
    }
}

// ---------------------------------------------------------------------------
extern "C" void kernel_launch(void* const* d_in, const int* in_sizes, int n_in,
                              void* d_out, int out_size, void* d_ws, size_t ws_size,
                              hipStream_t stream) {
    const float* X     = (const float*)d_in[0];
    const float* task  = (const float*)d_in[1];
    const float* Wtok  = (const float*)d_in[2];
    const float* btok  = (const float*)d_in[3];
    const float* Wptok = (const float*)d_in[4];
    const float* bptok = (const float*)d_in[5];
    const float* gamma = (const float*)d_in[6];
    const float* beta  = (const float*)d_in[7];
    const float* Wnet  = (const float*)d_in[8];
    const float* bnet  = (const float*)d_in[9];
    float* out = (float*)d_out;

    float* ws = (float*)d_ws;
    float* bank = ws;                                  // B*P*D = 4,587,520
    float* ptok = bank + (size_t)BB * PP * DD;         // B*D   =   458,752
    float* GF   = ptok + (size_t)BB * DD;              // P*D   =    17,920
    float* SG   = GF + PP * DD;                        // P
    float* ZC   = SG + PP;                             // P

    prep_gf<<<PP, 256, 0, stream>>>(gamma, beta, Wnet, bnet, GF, SG, ZC);
    prep_bank<<<dim3(77, 8), 256, 0, stream>>>(task, Wtok, btok, Wptok, bptok, bank, ptok);
    fused_kernel<<<dim3(NN / FR, BB), 448, 0, stream>>>(X, bank, ptok, GF, SG, ZC, out);
}